// Round 3
// baseline (256.871 us; speedup 1.0000x reference)
//
#include <hip/hip_runtime.h>

// ARModel: out[b,t,n,0] = (t==0) ? 0 : x[b,t-1,n,0]*w[0,0,0] + bias[0]
// B=64, T=288, N=2000, C=1, p=1, out_dim=1 (fp32 in / fp32 out).
// Memory-bound: 147.5 MB read + 147.5 MB write. fillBuffer shows 6.7 TB/s
// write-only; float4-copy ubench (plain ld/st) 6.29 TB/s -> floor ~47 us.
//
// History (kernel slice, inferred where not in top-5):
//  v2: all-NT, 1 f4/thread              -> ~65 us (4.5 TB/s user)
//  v3: CACHED loads + NT stores, 4/thr  -> 88.4 us REGRESSION (2.5 TB/s HBM)
//  v4: all-NT, 8 f4/thread              -> ~62 us. MLP depth is NOT the
//      limiter (8x outstanding loads bought only ~3 us).
//  v5 (this): single change vs v4 -- drop BOTH nontemporal hints. This is
//      the config of the 6.29 TB/s float4-copy ubench, never yet tested.
//      v3's regression may have been the NT-store/cached-load MIX, not the
//      cached loads. Plain loads also let x (147 MB < 256 MB LLC) go
//      LLC-resident across graph replays.

typedef float f4 __attribute__((ext_vector_type(4)));

static constexpr int kN4       = 500;                // N/4 float4 per t-row
static constexpr int kTN4      = 144000;             // T*N/4 float4 per batch
static constexpr int kJ        = 8;                  // f4 per thread
static constexpr int kPerBlock = 256 * kJ;           // 2048 f4 per block
static constexpr int kBlocksX  = (kTN4 + kPerBlock - 1) / kPerBlock;  // 71

__global__ __launch_bounds__(256) void ARModel_88880053223563_kernel(
    const f4* __restrict__ x,
    const float* __restrict__ w,
    const float* __restrict__ bias,
    f4* __restrict__ out)
{
    const int tid  = threadIdx.x;
    const int bx   = blockIdx.x;
    const int rem0 = bx * kPerBlock + tid;           // f4 idx within batch
    const int base = blockIdx.y * kTN4;              // batch offset (f4)
    const float wv = w[0];                           // s_load broadcast
    const float bv = bias[0];

    if (bx != 0 && bx != kBlocksX - 1) {
        // Fast path: no bounds checks, no t==0 row. 8 loads in flight.
        f4 v[kJ];
        #pragma unroll
        for (int j = 0; j < kJ; ++j)
            v[j] = x[base + rem0 + j * 256 - kN4];
        #pragma unroll
        for (int j = 0; j < kJ; ++j) {
            f4 o;
            o.x = fmaf(v[j].x, wv, bv);
            o.y = fmaf(v[j].y, wv, bv);
            o.z = fmaf(v[j].z, wv, bv);
            o.w = fmaf(v[j].w, wv, bv);
            out[base + rem0 + j * 256] = o;
        }
    } else {
        // Edge blocks: block 0 holds the t==0 zero rows (rem < 500),
        // block kBlocksX-1 holds the tail (rem >= kTN4).
        #pragma unroll
        for (int j = 0; j < kJ; ++j) {
            const int rem = rem0 + j * 256;
            if (rem >= kTN4) continue;
            f4 o = (f4){0.f, 0.f, 0.f, 0.f};   // t==0 rows: zero, NO bias
            if (rem >= kN4) {
                const f4 xi = x[base + rem - kN4];
                o.x = fmaf(xi.x, wv, bv);
                o.y = fmaf(xi.y, wv, bv);
                o.z = fmaf(xi.z, wv, bv);
                o.w = fmaf(xi.w, wv, bv);
            }
            out[base + rem] = o;
        }
    }
}

extern "C" void kernel_launch(void* const* d_in, const int* in_sizes, int n_in,
                              void* d_out, int out_size, void* d_ws, size_t ws_size,
                              hipStream_t stream) {
    const f4*    x    = (const f4*)d_in[0];
    const float* w    = (const float*)d_in[1];
    const float* bias = (const float*)d_in[2];
    f4*          out  = (f4*)d_out;

    // 144000 f4 per batch -> 71 blocks of 2048 f4 (tail guard), 64 batches.
    dim3 grid(kBlocksX, 64);
    ARModel_88880053223563_kernel<<<grid, dim3(256), 0, stream>>>(x, w, bias, out);
}

// Round 5
// 246.411 us; speedup vs baseline: 1.0425x; 1.0425x over previous
//
#include <hip/hip_runtime.h>

// ARModel: out[b,t,n,0] = (t==0) ? 0 : x[b,t-1,n,0]*w[0,0,0] + bias[0]
// B=64, T=288, N=2000, C=1, p=1, out_dim=1 (fp32 in / fp32 out).
// Memory-bound: 147.5 MB read + 147.5 MB write. fillBuffer (write-only)
// shows 6.6 TB/s in-harness; float4-copy ubench 6.29 TB/s -> ~47 us floor.
//
// Access-path matrix (kernel slice, by subtraction of ~179 us fills):
//  ld NT    / st NT    : ~62 us  (v4)
//  ld plain / st NT    :  88 us  (v3, 4/thr)
//  ld plain / st plain :  78 us  (v5)
//  ld NT    / st plain :  THIS (v6) -- pairwise deltas predict ~54 us.
// Lessons: NT loads essential (bypass L1/L2 allocation -> deeper MLP);
// under plain loads, plain write-back stores beat NT write-through by ~8us.
// (Round 4 was a GPUAcquisitionTimeout -- this is the unbenched v6 resubmit.)

typedef float f4 __attribute__((ext_vector_type(4)));

static constexpr int kN4       = 500;                // N/4 float4 per t-row
static constexpr int kTN4      = 144000;             // T*N/4 float4 per batch
static constexpr int kJ        = 8;                  // f4 per thread
static constexpr int kPerBlock = 256 * kJ;           // 2048 f4 per block
static constexpr int kBlocksX  = (kTN4 + kPerBlock - 1) / kPerBlock;  // 71

__global__ __launch_bounds__(256) void ARModel_88880053223563_kernel(
    const f4* __restrict__ x,
    const float* __restrict__ w,
    const float* __restrict__ bias,
    f4* __restrict__ out)
{
    const int tid  = threadIdx.x;
    const int bx   = blockIdx.x;
    const int rem0 = bx * kPerBlock + tid;           // f4 idx within batch
    const int base = blockIdx.y * kTN4;              // batch offset (f4)
    const float wv = w[0];                           // s_load broadcast
    const float bv = bias[0];

    if (bx != 0 && bx != kBlocksX - 1) {
        // Fast path: no bounds checks, no t==0 row. 8 NT loads in flight.
        f4 v[kJ];
        #pragma unroll
        for (int j = 0; j < kJ; ++j)
            v[j] = __builtin_nontemporal_load(&x[base + rem0 + j * 256 - kN4]);
        #pragma unroll
        for (int j = 0; j < kJ; ++j) {
            f4 o;
            o.x = fmaf(v[j].x, wv, bv);
            o.y = fmaf(v[j].y, wv, bv);
            o.z = fmaf(v[j].z, wv, bv);
            o.w = fmaf(v[j].w, wv, bv);
            out[base + rem0 + j * 256] = o;          // plain write-back store
        }
    } else {
        // Edge blocks: block 0 holds the t==0 zero rows (rem < 500),
        // block kBlocksX-1 holds the tail (rem >= kTN4).
        #pragma unroll
        for (int j = 0; j < kJ; ++j) {
            const int rem = rem0 + j * 256;
            if (rem >= kTN4) continue;
            f4 o = (f4){0.f, 0.f, 0.f, 0.f};   // t==0 rows: zero, NO bias
            if (rem >= kN4) {
                const f4 xi = __builtin_nontemporal_load(&x[base + rem - kN4]);
                o.x = fmaf(xi.x, wv, bv);
                o.y = fmaf(xi.y, wv, bv);
                o.z = fmaf(xi.z, wv, bv);
                o.w = fmaf(xi.w, wv, bv);
            }
            out[base + rem] = o;                     // plain write-back store
        }
    }
}

extern "C" void kernel_launch(void* const* d_in, const int* in_sizes, int n_in,
                              void* d_out, int out_size, void* d_ws, size_t ws_size,
                              hipStream_t stream) {
    const f4*    x    = (const f4*)d_in[0];
    const float* w    = (const float*)d_in[1];
    const float* bias = (const float*)d_in[2];
    f4*          out  = (f4*)d_out;

    // 144000 f4 per batch -> 71 blocks of 2048 f4 (tail guard), 64 batches.
    dim3 grid(kBlocksX, 64);
    ARModel_88880053223563_kernel<<<grid, dim3(256), 0, stream>>>(x, w, bias, out);
}

// Round 7
// 243.173 us; speedup vs baseline: 1.0563x; 1.0133x over previous
//
#include <hip/hip_runtime.h>

// ARModel: out[b,t,n,0] = (t==0) ? 0 : x[b,t-1,n,0]*w[0,0,0] + bias[0]
// B=64, T=288, N=2000, C=1, p=1, out_dim=1 (fp32 in / fp32 out).
// Memory-bound: 147.5 MB read + 147.5 MB write, every byte compulsory.
//
// FINAL: revert to best-measured config (v2, 241.77 us total).
// Access-path matrix (kernel slice; C~170.7 us harness overhead):
//  ld NT    / st NT    : ~62-71 us  (v2 J=1 / v4 J=8 -- equal, BEST)
//  ld NT    / st plain : ~76 us     (v6)
//  ld plain / st plain : ~86 us     (v5)
//  ld plain / st NT    :  88.4 us   (v3, measured directly)
// Lessons: plain loads halve FETCH_SIZE via LLC hits (v3: 72 MB) yet are
// SLOWEST -- the L1/L2 allocation path, not HBM bytes, limits them; NT
// bypasses it. MLP depth 1 vs 8 irrelevant. Mixed R/W stream sustains
// ~4.2-4.9 TB/s vs 6.65 TB/s write-only fills; no source-level lever
// (path flags, depth, grid shape) moved it beyond noise.
// (Rounds 4 and 6 were GPUAcquisitionTimeouts -- this is the v2 resubmit.)

typedef float f4 __attribute__((ext_vector_type(4)));

static constexpr int kN4  = 500;     // N/4 float4 per t-row
static constexpr int kTN4 = 144000;  // T*N/4 float4 per batch

__global__ __launch_bounds__(256) void ARModel_88880053223563_kernel(
    const f4* __restrict__ x,
    const float* __restrict__ w,
    const float* __restrict__ bias,
    f4* __restrict__ out)
{
    const int rem = blockIdx.x * 256 + threadIdx.x;  // float4 index within batch
    if (rem >= kTN4) return;
    const long i = (long)blockIdx.y * kTN4 + rem;

    f4 v;
    if (rem < kN4) {
        // t == 0 row stays zero (d_out is poisoned each call, must write).
        v = (f4){0.f, 0.f, 0.f, 0.f};
    } else {
        const f4 xi = __builtin_nontemporal_load(&x[i - kN4]);
        const float wv = w[0];   // uniform scalar loads (s_load broadcast)
        const float bv = bias[0];
        v.x = fmaf(xi.x, wv, bv);
        v.y = fmaf(xi.y, wv, bv);
        v.z = fmaf(xi.z, wv, bv);
        v.w = fmaf(xi.w, wv, bv);
    }
    __builtin_nontemporal_store(v, &out[i]);
}

extern "C" void kernel_launch(void* const* d_in, const int* in_sizes, int n_in,
                              void* d_out, int out_size, void* d_ws, size_t ws_size,
                              hipStream_t stream) {
    const f4*    x    = (const f4*)d_in[0];
    const float* w    = (const float*)d_in[1];
    const float* bias = (const float*)d_in[2];
    f4*          out  = (f4*)d_out;

    // 144000 float4 per batch -> 563 blocks of 256 (tail guard), 64 batches.
    dim3 grid((kTN4 + 255) / 256, 64);
    ARModel_88880053223563_kernel<<<grid, dim3(256), 0, stream>>>(x, w, bias, out);
}